// Round 1
// baseline (4361.464 us; speedup 1.0000x reference)
//
#include <hip/hip_runtime.h>
#include <math.h>

// ---------------- problem constants ----------------
constexpr int NB = 4;            // batch
constexpr int NC = 512;          // channels
constexpr int NH = 64, NW = 64;  // spatial
constexpr int NPOS = NH * NW;        // 4096
constexpr int NANCH = NPOS * 9;      // 36864 anchors/batch
constexpr int PRE_TOPN = 6000;
constexpr int POST_TOPN = 300;
constexpr int CAND_CAP = 40960;

// anchors for base_size=16, ratios {0.5,1,2}, scales {8,16,32} (verified vs numpy)
__device__ __constant__ float A9c[9][4] = {
  {-84.f,-40.f,99.f,55.f},   {-176.f,-88.f,191.f,103.f}, {-360.f,-184.f,375.f,199.f},
  {-56.f,-56.f,71.f,71.f},   {-120.f,-120.f,135.f,135.f},{-248.f,-248.f,263.f,263.f},
  {-36.f,-80.f,51.f,95.f},   {-80.f,-168.f,95.f,183.f},  {-168.f,-344.f,183.f,359.f}};

// ---------------- ws layout (bytes) ----------------
constexpr size_t OFF_WT    = 0;                       // 512*512*9*4      = 9,437,184
constexpr size_t OFF_CONV  = 9437184;                 // 4*512*4096*4     = 33,554,432
constexpr size_t OFF_HEAD  = 42991616;                // 4*54*4096*4      = 3,538,944
constexpr size_t OFF_SKEY  = 46530560;                // 4*36864*4        = 589,824
constexpr size_t OFF_BOX   = 47120384;                // 4*36864*4*4      = 2,359,296
constexpr size_t OFF_HIST  = 49479680;                // 4*4096*4         = 65,536
constexpr size_t OFF_HIST2 = 49545216;                // 4*256*4          = 4,096
constexpr size_t OFF_MISC  = 49549312;                // 256
constexpr size_t OFF_CKEY  = 49549568;                // 4*40960*4        = 655,360
constexpr size_t OFF_CIDX  = 50204928;                // 4*40960*4        = 655,360
constexpr size_t OFF_SBOX  = 50860288;                // 4*6000*4*4       = 384,000
// total ≈ 51.2 MB

// ---------------- weight transpose: W[ko][c][tap] -> Wt[c][tap][ko] ----------------
__global__ __launch_bounds__(256) void wtrans_k(const float* __restrict__ Wc,
                                               float* __restrict__ Wt) {
  int i = blockIdx.x * 256 + threadIdx.x;
  if (i >= 512 * 512 * 9) return;
  int ko = i / 4608; int r = i - ko * 4608; int c = r / 9; int tap = r - c * 9;
  Wt[((size_t)c * 9 + tap) * 512 + ko] = Wc[i];
}

// ---------------- 3x3 conv + bias + relu (fp32) ----------------
#define FMA16(Wv, A0, A1, A2, A3)                                              \
  acc[0][0] += (Wv).x*(A0); acc[0][1] += (Wv).x*(A1); acc[0][2] += (Wv).x*(A2); acc[0][3] += (Wv).x*(A3); \
  acc[1][0] += (Wv).y*(A0); acc[1][1] += (Wv).y*(A1); acc[1][2] += (Wv).y*(A2); acc[1][3] += (Wv).y*(A3); \
  acc[2][0] += (Wv).z*(A0); acc[2][1] += (Wv).z*(A1); acc[2][2] += (Wv).z*(A2); acc[2][3] += (Wv).z*(A3); \
  acc[3][0] += (Wv).w*(A0); acc[3][1] += (Wv).w*(A1); acc[3][2] += (Wv).w*(A2); acc[3][3] += (Wv).w*(A3);

__global__ __launch_bounds__(256) void conv3x3_relu_k(
    const float* __restrict__ in, const float* __restrict__ Wt,
    const float* __restrict__ bias, float* __restrict__ out) {
  __shared__ float Ilds[16][10][20];  // c, y+halo, x+halo (padded 18->20)
  __shared__ float Wlds[16][9][32];   // c, tap, ko
  const int ko0 = blockIdx.x * 32;
  const int ty0 = (blockIdx.y >> 2) * 8;
  const int tx0 = (blockIdx.y & 3) * 16;
  const int b   = blockIdx.z;
  const int tid = threadIdx.x;
  const int tk4  = (tid & 7) * 4;      // kout sub-tile base (4 kout)
  const int tyy  = (tid >> 3) & 7;     // row within tile
  const int txx4 = (tid >> 6) * 4;     // x sub-tile base (4 x)

  float acc[4][4] = {{0.f,0.f,0.f,0.f},{0.f,0.f,0.f,0.f},{0.f,0.f,0.f,0.f},{0.f,0.f,0.f,0.f}};
  const float* inb = in + (size_t)b * NC * NPOS;

  for (int c0 = 0; c0 < NC; c0 += 16) {
    __syncthreads();
    // stage input patch 16 x 10 x 18
    for (int e = tid; e < 16 * 10 * 18; e += 256) {
      int cc = e / 180; int rem = e - cc * 180; int yy = rem / 18; int xx = rem - yy * 18;
      int gy = ty0 + yy - 1, gx = tx0 + xx - 1;
      float v = 0.f;
      if ((unsigned)gy < 64u && (unsigned)gx < 64u)
        v = inb[(size_t)(c0 + cc) * NPOS + gy * 64 + gx];
      Ilds[cc][yy][xx] = v;
    }
    // stage weights (coalesced from transposed layout)
    for (int e = tid; e < 16 * 9 * 32; e += 256) {
      int ko = e & 31; int r = e >> 5; int tap = r % 9; int cc = r / 9;
      Wlds[cc][tap][ko] = Wt[(size_t)(c0 + cc) * 4608 + tap * 512 + ko0 + ko];
    }
    __syncthreads();
    #pragma unroll 4
    for (int cc = 0; cc < 16; ++cc) {
      #pragma unroll
      for (int dy = 0; dy < 3; ++dy) {
        const float* ir = &Ilds[cc][tyy + dy][txx4];
        float i0 = ir[0], i1 = ir[1], i2 = ir[2], i3 = ir[3], i4 = ir[4], i5 = ir[5];
        float4 w0 = *(const float4*)&Wlds[cc][dy * 3 + 0][tk4];
        float4 w1 = *(const float4*)&Wlds[cc][dy * 3 + 1][tk4];
        float4 w2 = *(const float4*)&Wlds[cc][dy * 3 + 2][tk4];
        FMA16(w0, i0, i1, i2, i3)
        FMA16(w1, i1, i2, i3, i4)
        FMA16(w2, i2, i3, i4, i5)
      }
    }
  }
  const int y = ty0 + tyy;
  #pragma unroll
  for (int i = 0; i < 4; ++i) {
    int ko = ko0 + tk4 + i;
    float bv = bias[ko];
    float4 v;
    v.x = fmaxf(acc[i][0] + bv, 0.f);
    v.y = fmaxf(acc[i][1] + bv, 0.f);
    v.z = fmaxf(acc[i][2] + bv, 0.f);
    v.w = fmaxf(acc[i][3] + bv, 0.f);
    *(float4*)&out[(((size_t)b * NC + ko) << 12) + y * 64 + tx0 + txx4] = v;
  }
}

// ---------------- 1x1 heads: 54 outputs (18 cls + 36 bbox) ----------------
__global__ __launch_bounds__(256) void head54_k(
    const float* __restrict__ conv, const float* __restrict__ Wcls,
    const float* __restrict__ bcls, const float* __restrict__ Wbbox,
    const float* __restrict__ bbbox, float* __restrict__ head) {
  __shared__ float Wl[64][54];
  const int b = blockIdx.y;
  const int pos = blockIdx.x * 256 + threadIdx.x;
  const int tid = threadIdx.x;
  float acc[54];
  #pragma unroll
  for (int o = 0; o < 54; ++o) acc[o] = 0.f;
  const float* cb = conv + ((size_t)b * NC << 12);
  for (int c0 = 0; c0 < NC; c0 += 64) {
    __syncthreads();
    for (int e = tid; e < 64 * 54; e += 256) {
      int o = e % 54; int c = e / 54;
      Wl[c][o] = (o < 18) ? Wcls[o * 512 + c0 + c] : Wbbox[(o - 18) * 512 + c0 + c];
    }
    __syncthreads();
    for (int c = 0; c < 64; ++c) {
      float v = cb[((size_t)(c0 + c) << 12) + pos];
      #pragma unroll
      for (int o2 = 0; o2 < 27; ++o2) {
        float2 w = *(const float2*)&Wl[c][o2 * 2];
        acc[o2 * 2]     += v * w.x;
        acc[o2 * 2 + 1] += v * w.y;
      }
    }
  }
  #pragma unroll
  for (int o = 0; o < 54; ++o) {
    float bv = (o < 18) ? bcls[o] : bbbox[o - 18];
    head[(((size_t)b * 54 + o) << 12) + pos] = acc[o] + bv;
  }
}

// ---------------- score + box decode + clip + coarse histogram ----------------
__global__ __launch_bounds__(256) void decode_k(
    const float* __restrict__ head, const float* __restrict__ im_info,
    float* __restrict__ boxes, unsigned* __restrict__ skeys, unsigned* __restrict__ hist) {
  int t = blockIdx.x * 256 + threadIdx.x;
  if (t >= NB * NANCH) return;
  int b = t / NANCH; int n = t - b * NANCH;
  int a = n % 9; int pos = n / 9;
  int x = pos & 63; int y = pos >> 6;
  const float* hb = head + ((size_t)b * 54 << 12);
  float s0 = hb[(a << 12) + pos];
  float s1 = hb[((9 + a) << 12) + pos];
  float m = fmaxf(s0, s1);
  float e0 = expf(s0 - m), e1 = expf(s1 - m);
  float score = e1 / (e0 + e1);
  int dbase = 18 + a * 4;
  float d0 = hb[((dbase + 0) << 12) + pos];
  float d1 = hb[((dbase + 1) << 12) + pos];
  float d2 = hb[((dbase + 2) << 12) + pos];
  float d3 = hb[((dbase + 3) << 12) + pos];
  float sx = x * 16.f, sy = y * 16.f;
  float ax1 = A9c[a][0] + sx, ay1 = A9c[a][1] + sy;
  float ax2 = A9c[a][2] + sx, ay2 = A9c[a][3] + sy;
  float aw = ax2 - ax1 + 1.f, ah = ay2 - ay1 + 1.f;
  float acx = ax1 + 0.5f * aw, acy = ay1 + 0.5f * ah;
  float pcx = d0 * aw + acx, pcy = d1 * ah + acy;
  float pw = expf(d2) * aw, ph = expf(d3) * ah;
  float imh = im_info[b * 3 + 0], imw = im_info[b * 3 + 1];
  float x1 = fminf(fmaxf(pcx - 0.5f * pw, 0.f), imw - 1.f);
  float y1 = fminf(fmaxf(pcy - 0.5f * ph, 0.f), imh - 1.f);
  float x2 = fminf(fmaxf(pcx + 0.5f * pw, 0.f), imw - 1.f);
  float y2 = fminf(fmaxf(pcy + 0.5f * ph, 0.f), imh - 1.f);
  *(float4*)&boxes[(size_t)t * 4] = make_float4(x1, y1, x2, y2);
  unsigned key = __float_as_uint(score);  // score>0 -> bits order == value order
  skeys[t] = key;
  atomicAdd(&hist[b * 4096 + (key >> 20)], 1u);
}

// ---------------- threshold select (2-level radix on float bits) ----------------
__global__ __launch_bounds__(256) void scan_hist_k(const unsigned* __restrict__ hist,
                                                  unsigned* __restrict__ misc) {
  int b = blockIdx.x;
  const unsigned* h = hist + b * 4096;
  __shared__ unsigned csum[256];
  int tid = threadIdx.x;
  unsigned s = 0;
  #pragma unroll
  for (int i = 0; i < 16; ++i) s += h[tid * 16 + i];
  csum[tid] = s;
  __syncthreads();
  if (tid == 0) {
    unsigned cum = 0; int chunk = 0;
    for (int c = 255; c >= 0; --c) {
      if (cum + csum[c] >= (unsigned)PRE_TOPN) { chunk = c; break; }
      cum += csum[c];
    }
    unsigned t1 = chunk * 16, cumAbove = cum;
    for (int i = 15; i >= 0; --i) {
      unsigned cnt = h[chunk * 16 + i];
      if (cum + cnt >= (unsigned)PRE_TOPN) { t1 = chunk * 16 + i; cumAbove = cum; break; }
      cum += cnt;
    }
    misc[b] = t1;          // boundary bin (top 12 bits)
    misc[4 + b] = cumAbove;
  }
}

__global__ __launch_bounds__(256) void hist2_k(const unsigned* __restrict__ skeys,
                                              const unsigned* __restrict__ misc,
                                              unsigned* __restrict__ hist2) {
  int t = blockIdx.x * 256 + threadIdx.x;
  if (t >= NB * NANCH) return;
  int b = t / NANCH;
  unsigned key = skeys[t];
  if ((key >> 20) == misc[b]) atomicAdd(&hist2[b * 256 + ((key >> 12) & 255u)], 1u);
}

__global__ void scan2_k(const unsigned* __restrict__ hist2, unsigned* __restrict__ misc) {
  int b = blockIdx.x;
  if (threadIdx.x != 0) return;
  unsigned cum = misc[4 + b];
  unsigned t1 = misc[b];
  unsigned T2 = t1 << 20;
  for (int s = 255; s >= 0; --s) {
    unsigned c = hist2[b * 256 + s];
    if (cum + c >= (unsigned)PRE_TOPN) { T2 = (t1 << 20) | ((unsigned)s << 12); break; }
    cum += c;
  }
  misc[8 + b] = T2;
}

__global__ __launch_bounds__(256) void compact_k(const unsigned* __restrict__ skeys,
                                                unsigned* __restrict__ misc,
                                                unsigned* __restrict__ ckey,
                                                unsigned* __restrict__ cidx) {
  int t = blockIdx.x * 256 + threadIdx.x;
  if (t >= NB * NANCH) return;
  int b = t / NANCH; int n = t - b * NANCH;
  unsigned key = skeys[t];
  if (key >= misc[8 + b]) {
    unsigned p = atomicAdd(&misc[12 + b], 1u);
    if (p < (unsigned)CAND_CAP) {
      ckey[(size_t)b * CAND_CAP + p] = key;
      cidx[(size_t)b * CAND_CAP + p] = (unsigned)n;
    }
  }
}

// ---------------- exact rank sort of candidates (desc score, asc index) ----------------
__global__ __launch_bounds__(256) void rank_scatter_k(
    const unsigned* __restrict__ ckey, const unsigned* __restrict__ cidx,
    const unsigned* __restrict__ misc, const float* __restrict__ boxes,
    float* __restrict__ sbox) {
  const int b = blockIdx.y;
  const int K = min((int)misc[12 + b], CAND_CAP);
  const int i = blockIdx.x * 256 + threadIdx.x;
  unsigned mykey = 0, myidx = 0;
  const bool active = i < K;
  if (active) {
    mykey = ckey[(size_t)b * CAND_CAP + i];
    myidx = cidx[(size_t)b * CAND_CAP + i];
  }
  int rank = 0;
  __shared__ unsigned skey[1024];
  __shared__ unsigned sidx[1024];
  for (int c0 = 0; c0 < K; c0 += 1024) {
    int n = min(1024, K - c0);
    __syncthreads();
    for (int e = threadIdx.x; e < n; e += 256) {
      skey[e] = ckey[(size_t)b * CAND_CAP + c0 + e];
      sidx[e] = cidx[(size_t)b * CAND_CAP + c0 + e];
    }
    __syncthreads();
    if (active) {
      for (int j = 0; j < n; ++j) {
        unsigned kj = skey[j];
        rank += (kj > mykey) || (kj == mykey && sidx[j] < myidx);
      }
    }
  }
  if (active && rank < PRE_TOPN) {
    float4 bx = *(const float4*)&boxes[((size_t)b * NANCH + myidx) * 4];
    *(float4*)&sbox[((size_t)b * PRE_TOPN + rank) * 4] = bx;
  }
}

// ---------------- sequential greedy NMS (matches reference argmax-over-valid) ----------------
__global__ __launch_bounds__(256) void nms_k(const float* __restrict__ sbox,
                                            float* __restrict__ out) {
  const int b = blockIdx.x;
  __shared__ unsigned long long valid[94];  // 6000 bits
  __shared__ int s_i;
  __shared__ float4 s_box;
  const int tid = threadIdx.x;
  for (int w = tid; w < 94; w += 256)
    valid[w] = (w == 93) ? ((1ULL << 48) - 1ULL) : ~0ULL;
  __syncthreads();
  const float* Bb = sbox + (size_t)b * PRE_TOPN * 4;
  float* O = out + (size_t)b * POST_TOPN * 5;
  int startw = 0;
  int done = POST_TOPN;
  for (int it = 0; it < POST_TOPN; ++it) {
    if (tid == 0) {
      int found = -1;
      for (int w = startw; w < 94; ++w) {
        unsigned long long v = valid[w];
        if (v) { found = w * 64 + __ffsll((unsigned long long)v) - 1; break; }
      }
      s_i = found;
    }
    __syncthreads();
    const int i = s_i;
    if (i < 0) { done = it; break; }
    startw = i >> 6;
    if (tid == 0) {
      float4 pb0 = *(const float4*)&Bb[(size_t)i * 4];
      s_box = pb0;
      O[it * 5 + 0] = (float)b;
      O[it * 5 + 1] = pb0.x; O[it * 5 + 2] = pb0.y;
      O[it * 5 + 3] = pb0.z; O[it * 5 + 4] = pb0.w;
    }
    __syncthreads();
    const float4 pb = s_box;
    const float parea = (pb.z - pb.x + 1.f) * (pb.w - pb.y + 1.f);
    const int jbase = (i >> 6) << 6;
    const int lane = tid & 63, wv = tid >> 6;
    for (int j0 = jbase; j0 < PRE_TOPN; j0 += 256) {
      int j = j0 + tid;
      bool sup = false;
      if (j < PRE_TOPN) {
        float4 q = *(const float4*)&Bb[(size_t)j * 4];
        float xx1 = fmaxf(pb.x, q.x), yy1 = fmaxf(pb.y, q.y);
        float xx2 = fminf(pb.z, q.z), yy2 = fminf(pb.w, q.w);
        float inter = fmaxf(xx2 - xx1 + 1.f, 0.f) * fmaxf(yy2 - yy1 + 1.f, 0.f);
        float area = (q.z - q.x + 1.f) * (q.w - q.y + 1.f);
        float iou = inter / (parea + area - inter);
        sup = iou > 0.7f;
      }
      unsigned long long mask = __ballot(sup);
      if (mask && lane == 0) {
        int word = (j0 >> 6) + wv;
        valid[word] &= ~mask;
      }
    }
    __syncthreads();
  }
  __syncthreads();
  for (int e = tid; e < (POST_TOPN - done) * 5; e += 256) {
    int r = done + e / 5; int c = e - (e / 5) * 5;
    O[r * 5 + c] = (c == 0) ? (float)b : 0.f;
  }
}

// ---------------- launch ----------------
extern "C" void kernel_launch(void* const* d_in, const int* in_sizes, int n_in,
                              void* d_out, int out_size, void* d_ws, size_t ws_size,
                              hipStream_t stream) {
  const float* base_feat = (const float*)d_in[0];
  const float* im_info   = (const float*)d_in[1];
  const float* W_conv    = (const float*)d_in[4];
  const float* b_conv    = (const float*)d_in[5];
  const float* W_cls     = (const float*)d_in[6];
  const float* b_cls     = (const float*)d_in[7];
  const float* W_bbox    = (const float*)d_in[8];
  const float* b_bbox    = (const float*)d_in[9];
  float* out = (float*)d_out;
  char* ws = (char*)d_ws;

  float*    Wt    = (float*)(ws + OFF_WT);
  float*    conv  = (float*)(ws + OFF_CONV);
  float*    head  = (float*)(ws + OFF_HEAD);
  unsigned* skeys = (unsigned*)(ws + OFF_SKEY);
  float*    boxes = (float*)(ws + OFF_BOX);
  unsigned* hist  = (unsigned*)(ws + OFF_HIST);
  unsigned* hist2 = (unsigned*)(ws + OFF_HIST2);
  unsigned* misc  = (unsigned*)(ws + OFF_MISC);
  unsigned* ckey  = (unsigned*)(ws + OFF_CKEY);
  unsigned* cidx  = (unsigned*)(ws + OFF_CIDX);
  float*    sbox  = (float*)(ws + OFF_SBOX);

  // zero hist + hist2 + misc (contiguous)
  hipMemsetAsync(ws + OFF_HIST, 0, 65536 + 4096 + 256, stream);

  wtrans_k<<<(512 * 512 * 9 + 255) / 256, 256, 0, stream>>>(W_conv, Wt);
  conv3x3_relu_k<<<dim3(16, 32, 4), 256, 0, stream>>>(base_feat, Wt, b_conv, conv);
  head54_k<<<dim3(16, 4), 256, 0, stream>>>(conv, W_cls, b_cls, W_bbox, b_bbox, head);
  decode_k<<<(NB * NANCH) / 256, 256, 0, stream>>>(head, im_info, boxes, skeys, hist);
  scan_hist_k<<<4, 256, 0, stream>>>(hist, misc);
  hist2_k<<<(NB * NANCH) / 256, 256, 0, stream>>>(skeys, misc, hist2);
  scan2_k<<<4, 64, 0, stream>>>(hist2, misc);
  compact_k<<<(NB * NANCH) / 256, 256, 0, stream>>>(skeys, misc, ckey, cidx);
  rank_scatter_k<<<dim3(CAND_CAP / 256, 4), 256, 0, stream>>>(ckey, cidx, misc, boxes, sbox);
  nms_k<<<4, 256, 0, stream>>>(sbox, out);
}

// Round 3
// 2827.086 us; speedup vs baseline: 1.5427x; 1.5427x over previous
//
#include <hip/hip_runtime.h>
#include <math.h>

// ---------------- problem constants ----------------
constexpr int NB = 4;            // batch
constexpr int NC = 512;          // channels
constexpr int NH = 64, NW = 64;  // spatial
constexpr int NPOS = NH * NW;        // 4096
constexpr int NANCH = NPOS * 9;      // 36864 anchors/batch
constexpr int PRE_TOPN = 6000;
constexpr int POST_TOPN = 300;
constexpr int CAND_CAP = 40960;
constexpr int MROW = 96;             // mask row stride in u64 (94 used)

// anchors for base_size=16, ratios {0.5,1,2}, scales {8,16,32} (verified vs numpy)
__device__ __constant__ float A9c[9][4] = {
  {-84.f,-40.f,99.f,55.f},   {-176.f,-88.f,191.f,103.f}, {-360.f,-184.f,375.f,199.f},
  {-56.f,-56.f,71.f,71.f},   {-120.f,-120.f,135.f,135.f},{-248.f,-248.f,263.f,263.f},
  {-36.f,-80.f,51.f,95.f},   {-80.f,-168.f,95.f,183.f},  {-168.f,-344.f,183.f,359.f}};

// ---------------- ws layout (bytes) ----------------
constexpr size_t OFF_WT    = 0;                       // 512*512*9*4      = 9,437,184
constexpr size_t OFF_CONV  = 9437184;                 // 4*512*4096*4     = 33,554,432 (reused as IoU mask after head54)
constexpr size_t OFF_MASK  = OFF_CONV;                // 4*6000*96*8      = 18,432,000 (overlay)
constexpr size_t OFF_HEAD  = 42991616;                // 4*54*4096*4      = 3,538,944
constexpr size_t OFF_SKEY  = 46530560;                // 4*36864*4        = 589,824
constexpr size_t OFF_BOX   = 47120384;                // 4*36864*4*4      = 2,359,296
constexpr size_t OFF_HIST  = 49479680;                // 4*4096*4         = 65,536
constexpr size_t OFF_HIST2 = 49545216;                // 4*256*4          = 4,096
constexpr size_t OFF_MISC  = 49549312;                // 256
constexpr size_t OFF_CKEY  = 49549568;                // 4*40960*4        = 655,360
constexpr size_t OFF_CIDX  = 50204928;                // 4*40960*4        = 655,360
constexpr size_t OFF_SBOX  = 50860288;                // 4*6000*4*4       = 384,000
// total ≈ 51.2 MB

// ---------------- weight transpose: W[ko][c][tap] -> Wt[c][tap][ko] ----------------
__global__ __launch_bounds__(256) void wtrans_k(const float* __restrict__ Wc,
                                               float* __restrict__ Wt) {
  int i = blockIdx.x * 256 + threadIdx.x;
  if (i >= 512 * 512 * 9) return;
  int ko = i / 4608; int r = i - ko * 4608; int c = r / 9; int tap = r - c * 9;
  Wt[((size_t)c * 9 + tap) * 512 + ko] = Wc[i];
}

// ---------------- 3x3 conv + bias + relu (fp32) ----------------
#define FMA16(Wv, A0, A1, A2, A3)                                              \
  acc[0][0] += (Wv).x*(A0); acc[0][1] += (Wv).x*(A1); acc[0][2] += (Wv).x*(A2); acc[0][3] += (Wv).x*(A3); \
  acc[1][0] += (Wv).y*(A0); acc[1][1] += (Wv).y*(A1); acc[1][2] += (Wv).y*(A2); acc[1][3] += (Wv).y*(A3); \
  acc[2][0] += (Wv).z*(A0); acc[2][1] += (Wv).z*(A1); acc[2][2] += (Wv).z*(A2); acc[2][3] += (Wv).z*(A3); \
  acc[3][0] += (Wv).w*(A0); acc[3][1] += (Wv).w*(A1); acc[3][2] += (Wv).w*(A2); acc[3][3] += (Wv).w*(A3);

__global__ __launch_bounds__(256) void conv3x3_relu_k(
    const float* __restrict__ in, const float* __restrict__ Wt,
    const float* __restrict__ bias, float* __restrict__ out) {
  __shared__ float Ilds[16][10][20];  // c, y+halo, x+halo (padded 18->20)
  __shared__ float Wlds[16][9][32];   // c, tap, ko
  const int ko0 = blockIdx.x * 32;
  const int ty0 = (blockIdx.y >> 2) * 8;
  const int tx0 = (blockIdx.y & 3) * 16;
  const int b   = blockIdx.z;
  const int tid = threadIdx.x;
  const int tk4  = (tid & 7) * 4;      // kout sub-tile base (4 kout)
  const int tyy  = (tid >> 3) & 7;     // row within tile
  const int txx4 = (tid >> 6) * 4;     // x sub-tile base (4 x)

  float acc[4][4] = {{0.f,0.f,0.f,0.f},{0.f,0.f,0.f,0.f},{0.f,0.f,0.f,0.f},{0.f,0.f,0.f,0.f}};
  const float* inb = in + (size_t)b * NC * NPOS;

  for (int c0 = 0; c0 < NC; c0 += 16) {
    __syncthreads();
    // stage input patch 16 x 10 x 18
    for (int e = tid; e < 16 * 10 * 18; e += 256) {
      int cc = e / 180; int rem = e - cc * 180; int yy = rem / 18; int xx = rem - yy * 18;
      int gy = ty0 + yy - 1, gx = tx0 + xx - 1;
      float v = 0.f;
      if ((unsigned)gy < 64u && (unsigned)gx < 64u)
        v = inb[(size_t)(c0 + cc) * NPOS + gy * 64 + gx];
      Ilds[cc][yy][xx] = v;
    }
    // stage weights (coalesced from transposed layout)
    for (int e = tid; e < 16 * 9 * 32; e += 256) {
      int ko = e & 31; int r = e >> 5; int tap = r % 9; int cc = r / 9;
      Wlds[cc][tap][ko] = Wt[(size_t)(c0 + cc) * 4608 + tap * 512 + ko0 + ko];
    }
    __syncthreads();
    #pragma unroll 4
    for (int cc = 0; cc < 16; ++cc) {
      #pragma unroll
      for (int dy = 0; dy < 3; ++dy) {
        const float* ir = &Ilds[cc][tyy + dy][txx4];
        float i0 = ir[0], i1 = ir[1], i2 = ir[2], i3 = ir[3], i4 = ir[4], i5 = ir[5];
        float4 w0 = *(const float4*)&Wlds[cc][dy * 3 + 0][tk4];
        float4 w1 = *(const float4*)&Wlds[cc][dy * 3 + 1][tk4];
        float4 w2 = *(const float4*)&Wlds[cc][dy * 3 + 2][tk4];
        FMA16(w0, i0, i1, i2, i3)
        FMA16(w1, i1, i2, i3, i4)
        FMA16(w2, i2, i3, i4, i5)
      }
    }
  }
  const int y = ty0 + tyy;
  #pragma unroll
  for (int i = 0; i < 4; ++i) {
    int ko = ko0 + tk4 + i;
    float bv = bias[ko];
    float4 v;
    v.x = fmaxf(acc[i][0] + bv, 0.f);
    v.y = fmaxf(acc[i][1] + bv, 0.f);
    v.z = fmaxf(acc[i][2] + bv, 0.f);
    v.w = fmaxf(acc[i][3] + bv, 0.f);
    *(float4*)&out[(((size_t)b * NC + ko) << 12) + y * 64 + tx0 + txx4] = v;
  }
}

// ---------------- 1x1 heads: 54 outputs (18 cls + 36 bbox) ----------------
__global__ __launch_bounds__(256) void head54_k(
    const float* __restrict__ conv, const float* __restrict__ Wcls,
    const float* __restrict__ bcls, const float* __restrict__ Wbbox,
    const float* __restrict__ bbbox, float* __restrict__ head) {
  __shared__ float Wl[64][54];
  const int b = blockIdx.y;
  const int pos = blockIdx.x * 256 + threadIdx.x;
  const int tid = threadIdx.x;
  float acc[54];
  #pragma unroll
  for (int o = 0; o < 54; ++o) acc[o] = 0.f;
  const float* cb = conv + ((size_t)b * NC << 12);
  for (int c0 = 0; c0 < NC; c0 += 64) {
    __syncthreads();
    for (int e = tid; e < 64 * 54; e += 256) {
      int o = e % 54; int c = e / 54;
      Wl[c][o] = (o < 18) ? Wcls[o * 512 + c0 + c] : Wbbox[(o - 18) * 512 + c0 + c];
    }
    __syncthreads();
    for (int c = 0; c < 64; ++c) {
      float v = cb[((size_t)(c0 + c) << 12) + pos];
      #pragma unroll
      for (int o2 = 0; o2 < 27; ++o2) {
        float2 w = *(const float2*)&Wl[c][o2 * 2];
        acc[o2 * 2]     += v * w.x;
        acc[o2 * 2 + 1] += v * w.y;
      }
    }
  }
  #pragma unroll
  for (int o = 0; o < 54; ++o) {
    float bv = (o < 18) ? bcls[o] : bbbox[o - 18];
    head[(((size_t)b * 54 + o) << 12) + pos] = acc[o] + bv;
  }
}

// ---------------- score + box decode + clip + coarse histogram ----------------
__global__ __launch_bounds__(256) void decode_k(
    const float* __restrict__ head, const float* __restrict__ im_info,
    float* __restrict__ boxes, unsigned* __restrict__ skeys, unsigned* __restrict__ hist) {
  int t = blockIdx.x * 256 + threadIdx.x;
  if (t >= NB * NANCH) return;
  int b = t / NANCH; int n = t - b * NANCH;
  int a = n % 9; int pos = n / 9;
  int x = pos & 63; int y = pos >> 6;
  const float* hb = head + ((size_t)b * 54 << 12);
  float s0 = hb[(a << 12) + pos];
  float s1 = hb[((9 + a) << 12) + pos];
  float m = fmaxf(s0, s1);
  float e0 = expf(s0 - m), e1 = expf(s1 - m);
  float score = e1 / (e0 + e1);
  int dbase = 18 + a * 4;
  float d0 = hb[((dbase + 0) << 12) + pos];
  float d1 = hb[((dbase + 1) << 12) + pos];
  float d2 = hb[((dbase + 2) << 12) + pos];
  float d3 = hb[((dbase + 3) << 12) + pos];
  float sx = x * 16.f, sy = y * 16.f;
  float ax1 = A9c[a][0] + sx, ay1 = A9c[a][1] + sy;
  float ax2 = A9c[a][2] + sx, ay2 = A9c[a][3] + sy;
  float aw = ax2 - ax1 + 1.f, ah = ay2 - ay1 + 1.f;
  float acx = ax1 + 0.5f * aw, acy = ay1 + 0.5f * ah;
  float pcx = d0 * aw + acx, pcy = d1 * ah + acy;
  float pw = expf(d2) * aw, ph = expf(d3) * ah;
  float imh = im_info[b * 3 + 0], imw = im_info[b * 3 + 1];
  float x1 = fminf(fmaxf(pcx - 0.5f * pw, 0.f), imw - 1.f);
  float y1 = fminf(fmaxf(pcy - 0.5f * ph, 0.f), imh - 1.f);
  float x2 = fminf(fmaxf(pcx + 0.5f * pw, 0.f), imw - 1.f);
  float y2 = fminf(fmaxf(pcy + 0.5f * ph, 0.f), imh - 1.f);
  *(float4*)&boxes[(size_t)t * 4] = make_float4(x1, y1, x2, y2);
  unsigned key = __float_as_uint(score);  // score>0 -> bits order == value order
  skeys[t] = key;
  atomicAdd(&hist[b * 4096 + (key >> 20)], 1u);
}

// ---------------- threshold select (2-level radix on float bits) ----------------
__global__ __launch_bounds__(256) void scan_hist_k(const unsigned* __restrict__ hist,
                                                  unsigned* __restrict__ misc) {
  int b = blockIdx.x;
  const unsigned* h = hist + b * 4096;
  __shared__ unsigned csum[256];
  int tid = threadIdx.x;
  unsigned s = 0;
  #pragma unroll
  for (int i = 0; i < 16; ++i) s += h[tid * 16 + i];
  csum[tid] = s;
  __syncthreads();
  if (tid == 0) {
    unsigned cum = 0; int chunk = 0;
    for (int c = 255; c >= 0; --c) {
      if (cum + csum[c] >= (unsigned)PRE_TOPN) { chunk = c; break; }
      cum += csum[c];
    }
    unsigned t1 = chunk * 16, cumAbove = cum;
    for (int i = 15; i >= 0; --i) {
      unsigned cnt = h[chunk * 16 + i];
      if (cum + cnt >= (unsigned)PRE_TOPN) { t1 = chunk * 16 + i; cumAbove = cum; break; }
      cum += cnt;
    }
    misc[b] = t1;          // boundary bin (top 12 bits)
    misc[4 + b] = cumAbove;
  }
}

__global__ __launch_bounds__(256) void hist2_k(const unsigned* __restrict__ skeys,
                                              const unsigned* __restrict__ misc,
                                              unsigned* __restrict__ hist2) {
  int t = blockIdx.x * 256 + threadIdx.x;
  if (t >= NB * NANCH) return;
  int b = t / NANCH;
  unsigned key = skeys[t];
  if ((key >> 20) == misc[b]) atomicAdd(&hist2[b * 256 + ((key >> 12) & 255u)], 1u);
}

__global__ void scan2_k(const unsigned* __restrict__ hist2, unsigned* __restrict__ misc) {
  int b = blockIdx.x;
  if (threadIdx.x != 0) return;
  unsigned cum = misc[4 + b];
  unsigned t1 = misc[b];
  unsigned T2 = t1 << 20;
  for (int s = 255; s >= 0; --s) {
    unsigned c = hist2[b * 256 + s];
    if (cum + c >= (unsigned)PRE_TOPN) { T2 = (t1 << 20) | ((unsigned)s << 12); break; }
    cum += c;
  }
  misc[8 + b] = T2;
}

__global__ __launch_bounds__(256) void compact_k(const unsigned* __restrict__ skeys,
                                                unsigned* __restrict__ misc,
                                                unsigned* __restrict__ ckey,
                                                unsigned* __restrict__ cidx) {
  int t = blockIdx.x * 256 + threadIdx.x;
  if (t >= NB * NANCH) return;
  int b = t / NANCH; int n = t - b * NANCH;
  unsigned key = skeys[t];
  if (key >= misc[8 + b]) {
    unsigned p = atomicAdd(&misc[12 + b], 1u);
    if (p < (unsigned)CAND_CAP) {
      ckey[(size_t)b * CAND_CAP + p] = key;
      cidx[(size_t)b * CAND_CAP + p] = (unsigned)n;
    }
  }
}

// ---------------- exact rank sort of candidates (desc score, asc index) ----------------
__global__ __launch_bounds__(256) void rank_scatter_k(
    const unsigned* __restrict__ ckey, const unsigned* __restrict__ cidx,
    const unsigned* __restrict__ misc, const float* __restrict__ boxes,
    float* __restrict__ sbox) {
  const int b = blockIdx.y;
  const int K = min((int)misc[12 + b], CAND_CAP);
  const int i = blockIdx.x * 256 + threadIdx.x;
  unsigned mykey = 0, myidx = 0;
  const bool active = i < K;
  if (active) {
    mykey = ckey[(size_t)b * CAND_CAP + i];
    myidx = cidx[(size_t)b * CAND_CAP + i];
  }
  int rank = 0;
  __shared__ unsigned skey[1024];
  __shared__ unsigned sidx[1024];
  for (int c0 = 0; c0 < K; c0 += 1024) {
    int n = min(1024, K - c0);
    __syncthreads();
    for (int e = threadIdx.x; e < n; e += 256) {
      skey[e] = ckey[(size_t)b * CAND_CAP + c0 + e];
      sidx[e] = cidx[(size_t)b * CAND_CAP + c0 + e];
    }
    __syncthreads();
    if (active) {
      for (int j = 0; j < n; ++j) {
        unsigned kj = skey[j];
        rank += (kj > mykey) || (kj == mykey && sidx[j] < myidx);
      }
    }
  }
  if (active && rank < PRE_TOPN) {
    float4 bx = *(const float4*)&boxes[((size_t)b * NANCH + myidx) * 4];
    *(float4*)&sbox[((size_t)b * PRE_TOPN + rank) * 4] = bx;
  }
}

// ---------------- IoU suppression bit-matrix: mask[b][i][w] bit q = (iou(i, w*64+q) > 0.7) --
__global__ __launch_bounds__(256) void iou_mask_k(const float* __restrict__ sbox,
                                                  unsigned long long* __restrict__ mask) {
  __shared__ float4 jb[3008];  // 48 KiB j-tile
  __shared__ float4 ib[32];    // i-tile
  const int b  = blockIdx.z;
  const int i0 = blockIdx.y * 32;
  const int w0 = blockIdx.x * 47;
  const int j0 = w0 * 64;
  const int nj = min(3008, PRE_TOPN - j0);
  const int tid = threadIdx.x;
  const float4* S = (const float4*)(sbox + (size_t)b * PRE_TOPN * 4);
  for (int e = tid; e < nj; e += 256) jb[e] = S[j0 + e];
  if (tid < 32 && i0 + tid < PRE_TOPN) ib[tid] = S[i0 + tid];
  __syncthreads();
  for (int idx = tid; idx < 32 * 47; idx += 256) {
    const int il = idx / 47, wl = idx - il * 47;
    const int i = i0 + il;
    if (i >= PRE_TOPN) continue;
    const float4 p = ib[il];
    const float parea = (p.z - p.x + 1.f) * (p.w - p.y + 1.f);
    unsigned long long m = 0;
    const int jb0 = wl * 64;
    #pragma unroll 8
    for (int q = 0; q < 64; ++q) {
      const int j = jb0 + q;   // j <= 46*64+63 = 3007 < 3008: always in-bounds
      const float4 qb = jb[j];
      float xx1 = fmaxf(p.x, qb.x), yy1 = fmaxf(p.y, qb.y);
      float xx2 = fminf(p.z, qb.z), yy2 = fminf(p.w, qb.w);
      float inter = fmaxf(xx2 - xx1 + 1.f, 0.f) * fmaxf(yy2 - yy1 + 1.f, 0.f);
      float area = (qb.z - qb.x + 1.f) * (qb.w - qb.y + 1.f);
      float iou = inter / (parea + area - inter);
      if (iou > 0.7f && j < nj) m |= (1ull << q);
    }
    mask[((size_t)b * PRE_TOPN + i) * MROW + w0 + wl] = m;
  }
}

// ---------------- wave-synchronous greedy pick: valid bitset in VGPRs ----------------
__device__ inline unsigned long long shfl_u64(unsigned long long v, int src) {
  int lo = __shfl((int)(unsigned)v, src, 64);
  int hi = __shfl((int)(unsigned)(v >> 32), src, 64);
  return ((unsigned long long)(unsigned)hi << 32) | (unsigned)lo;
}

__global__ __launch_bounds__(64) void nms_pick_k(const float* __restrict__ sbox,
                                                 const unsigned long long* __restrict__ mask,
                                                 float* __restrict__ out) {
  const int b = blockIdx.x;
  const int lane = threadIdx.x;
  // valid words: va = word[lane] (0..63), vb = word[64+lane] (lane<30; word 93 partial 48 bits)
  unsigned long long va = ~0ull;
  unsigned long long vb = (lane < 29) ? ~0ull : (lane == 29 ? ((1ull << 48) - 1ull) : 0ull);
  const float* Bb = sbox + (size_t)b * PRE_TOPN * 4;
  float* O = out + (size_t)b * POST_TOPN * 5;
  int done = POST_TOPN;
  for (int it = 0; it < POST_TOPN; ++it) {
    unsigned long long ba = __ballot(va != 0ull);
    unsigned long long bb = __ballot(vb != 0ull);
    int w; unsigned long long word;
    if (ba) {
      w = __ffsll((long long)ba) - 1;
      word = shfl_u64(va, w);
    } else if (bb) {
      w = __ffsll((long long)bb) - 1;
      word = shfl_u64(vb, w);
      w += 64;
    } else { done = it; break; }
    const int i = (w << 6) + __ffsll((long long)word) - 1;
    const unsigned long long* row = mask + ((size_t)b * PRE_TOPN + i) * MROW;
    unsigned long long ra = row[lane];
    unsigned long long rb = (lane < 30) ? row[64 + lane] : 0ull;
    // output (off the critical path: independent of va/vb update)
    if (lane < 4) O[it * 5 + 1 + lane] = Bb[(size_t)i * 4 + lane];
    if (lane == 4) O[it * 5] = (float)b;
    va &= ~ra;
    vb &= ~rb;
  }
  for (int e = lane; e < (POST_TOPN - done) * 5; e += 64) {
    int r = done + e / 5; int c = e - (e / 5) * 5;
    O[r * 5 + c] = (c == 0) ? (float)b : 0.f;
  }
}

// ---------------- launch ----------------
extern "C" void kernel_launch(void* const* d_in, const int* in_sizes, int n_in,
                              void* d_out, int out_size, void* d_ws, size_t ws_size,
                              hipStream_t stream) {
  const float* base_feat = (const float*)d_in[0];
  const float* im_info   = (const float*)d_in[1];
  const float* W_conv    = (const float*)d_in[4];
  const float* b_conv    = (const float*)d_in[5];
  const float* W_cls     = (const float*)d_in[6];
  const float* b_cls     = (const float*)d_in[7];
  const float* W_bbox    = (const float*)d_in[8];
  const float* b_bbox    = (const float*)d_in[9];
  float* out = (float*)d_out;
  char* ws = (char*)d_ws;

  float*    Wt    = (float*)(ws + OFF_WT);
  float*    conv  = (float*)(ws + OFF_CONV);
  unsigned long long* mask = (unsigned long long*)(ws + OFF_MASK);  // overlays conv (dead after head54)
  float*    head  = (float*)(ws + OFF_HEAD);
  unsigned* skeys = (unsigned*)(ws + OFF_SKEY);
  float*    boxes = (float*)(ws + OFF_BOX);
  unsigned* hist  = (unsigned*)(ws + OFF_HIST);
  unsigned* hist2 = (unsigned*)(ws + OFF_HIST2);
  unsigned* misc  = (unsigned*)(ws + OFF_MISC);
  unsigned* ckey  = (unsigned*)(ws + OFF_CKEY);
  unsigned* cidx  = (unsigned*)(ws + OFF_CIDX);
  float*    sbox  = (float*)(ws + OFF_SBOX);

  // zero hist + hist2 + misc (contiguous)
  hipMemsetAsync(ws + OFF_HIST, 0, 65536 + 4096 + 256, stream);

  wtrans_k<<<(512 * 512 * 9 + 255) / 256, 256, 0, stream>>>(W_conv, Wt);
  conv3x3_relu_k<<<dim3(16, 32, 4), 256, 0, stream>>>(base_feat, Wt, b_conv, conv);
  head54_k<<<dim3(16, 4), 256, 0, stream>>>(conv, W_cls, b_cls, W_bbox, b_bbox, head);
  decode_k<<<(NB * NANCH) / 256, 256, 0, stream>>>(head, im_info, boxes, skeys, hist);
  scan_hist_k<<<4, 256, 0, stream>>>(hist, misc);
  hist2_k<<<(NB * NANCH) / 256, 256, 0, stream>>>(skeys, misc, hist2);
  scan2_k<<<4, 64, 0, stream>>>(hist2, misc);
  compact_k<<<(NB * NANCH) / 256, 256, 0, stream>>>(skeys, misc, ckey, cidx);
  rank_scatter_k<<<dim3(CAND_CAP / 256, 4), 256, 0, stream>>>(ckey, cidx, misc, boxes, sbox);
  iou_mask_k<<<dim3(2, 188, 4), 256, 0, stream>>>(sbox, mask);
  nms_pick_k<<<4, 64, 0, stream>>>(sbox, mask, out);
}

// Round 4
// 2355.424 us; speedup vs baseline: 1.8517x; 1.2002x over previous
//
#include <hip/hip_runtime.h>
#include <math.h>

// ---------------- problem constants ----------------
constexpr int NB = 4;            // batch
constexpr int NC = 512;          // channels
constexpr int NH = 64, NW = 64;  // spatial
constexpr int NPOS = NH * NW;        // 4096
constexpr int NANCH = NPOS * 9;      // 36864 anchors/batch
constexpr int PRE_TOPN = 6000;
constexpr int POST_TOPN = 300;
constexpr int CAND_CAP = 40960;
constexpr int MROW = 96;             // mask row stride in u64 (94 used)

// anchors for base_size=16, ratios {0.5,1,2}, scales {8,16,32} (verified vs numpy)
__device__ __constant__ float A9c[9][4] = {
  {-84.f,-40.f,99.f,55.f},   {-176.f,-88.f,191.f,103.f}, {-360.f,-184.f,375.f,199.f},
  {-56.f,-56.f,71.f,71.f},   {-120.f,-120.f,135.f,135.f},{-248.f,-248.f,263.f,263.f},
  {-36.f,-80.f,51.f,95.f},   {-80.f,-168.f,95.f,183.f},  {-168.f,-344.f,183.f,359.f}};

// ---------------- ws layout (bytes) ----------------
constexpr size_t OFF_WT    = 0;                       // 512*512*9*4      = 9,437,184
constexpr size_t OFF_CONV  = 9437184;                 // 4*512*4096*4     = 33,554,432 (reused as IoU mask after heads)
constexpr size_t OFF_MASK  = OFF_CONV;                // 4*6000*96*8      = 18,432,000 (overlay)
constexpr size_t OFF_HEAD  = 42991616;                // 4*54*4096*4      = 3,538,944
constexpr size_t OFF_SKEY  = 46530560;                // 4*36864*4        = 589,824
constexpr size_t OFF_BOX   = 47120384;                // 4*36864*4*4      = 2,359,296
constexpr size_t OFF_HIST  = 49479680;                // 4*4096*4         = 65,536
constexpr size_t OFF_HIST2 = 49545216;                // 4*256*4          = 4,096
constexpr size_t OFF_MISC  = 49549312;                // 256
constexpr size_t OFF_CKEY  = 49549568;                // 4*40960*4        = 655,360
constexpr size_t OFF_CIDX  = 50204928;                // 4*40960*4        = 655,360
constexpr size_t OFF_SBOX  = 50860288;                // 4*6000*4*4       = 384,000
// total ≈ 51.2 MB

// ---------------- weight transpose: W[ko][c][tap] -> Wt[c][tap][ko] ----------------
__global__ __launch_bounds__(256) void wtrans_k(const float* __restrict__ Wc,
                                               float* __restrict__ Wt) {
  int i = blockIdx.x * 256 + threadIdx.x;
  if (i >= 512 * 512 * 9) return;
  int ko = i / 4608; int r = i - ko * 4608; int c = r / 9; int tap = r - c * 9;
  Wt[((size_t)c * 9 + tap) * 512 + ko] = Wc[i];
}

// ---------------- 3x3 conv + bias + relu (fp32, 8ko x 4x per thread) ----------------
// Per-output accumulation order: c ascending, dy ascending, dx ascending —
// bit-identical to the R1/R3-passing kernel (selection depends on exact fp32 bits).
__global__ __launch_bounds__(256, 4) void conv3x3_relu_k(
    const float* __restrict__ in, const float* __restrict__ Wt,
    const float* __restrict__ bias, float* __restrict__ out) {
  __shared__ float Ilds[8][10][20];   // c, y+halo, x+halo (padded 18->20)
  __shared__ float Wlds[8][9][64];    // c, tap, ko  (flat-linear staging)
  const int ko0 = blockIdx.x * 64;        // 8 ko-blocks
  const int ty0 = (blockIdx.y >> 2) * 8;  // 8 y-tiles
  const int tx0 = (blockIdx.y & 3) * 16;  // 4 x-tiles
  const int b   = blockIdx.z;
  const int tid = threadIdx.x;
  const int tk8  = (tid & 7) * 8;      // 8 kout per thread
  const int tyy  = (tid >> 3) & 7;     // row within tile
  const int txx4 = (tid >> 6) * 4;     // 4 x per thread

  float acc[8][4] = {};
  const float* inb = in + (size_t)b * NC * NPOS;

  for (int c0 = 0; c0 < NC; c0 += 8) {
    __syncthreads();
    // stage input patch 8 x 10 x 18 (1440 elems)
    for (int e = tid; e < 8 * 10 * 18; e += 256) {
      int cc = e / 180; int rem = e - cc * 180; int yy = rem / 18; int xx = rem - yy * 18;
      int gy = ty0 + yy - 1, gx = tx0 + xx - 1;
      float v = 0.f;
      if ((unsigned)gy < 64u && (unsigned)gx < 64u)
        v = inb[(size_t)(c0 + cc) * NPOS + gy * 64 + gx];
      Ilds[cc][yy][xx] = v;
    }
    // stage weights 8 x 9 x 64 = 4608 elems; destination is linear in e
    for (int e = tid; e < 8 * 9 * 64; e += 256) {
      int ko = e & 63; int r = e >> 6; int tap = r % 9; int cc = r / 9;
      ((float*)Wlds)[e] = Wt[(size_t)(c0 + cc) * 4608 + tap * 512 + ko0 + ko];
    }
    __syncthreads();
    #pragma unroll 2
    for (int cc = 0; cc < 8; ++cc) {
      #pragma unroll
      for (int dy = 0; dy < 3; ++dy) {
        const float* ir = &Ilds[cc][tyy + dy][txx4];
        float av[6];
        av[0]=ir[0]; av[1]=ir[1]; av[2]=ir[2]; av[3]=ir[3]; av[4]=ir[4]; av[5]=ir[5];
        #pragma unroll
        for (int dx = 0; dx < 3; ++dx) {
          const float4 wa = *(const float4*)&Wlds[cc][dy * 3 + dx][tk8];
          const float4 wb = *(const float4*)&Wlds[cc][dy * 3 + dx][tk8 + 4];
          const float a0 = av[dx], a1 = av[dx+1], a2 = av[dx+2], a3 = av[dx+3];
          float wk[8] = {wa.x, wa.y, wa.z, wa.w, wb.x, wb.y, wb.z, wb.w};
          #pragma unroll
          for (int k = 0; k < 8; ++k) {
            acc[k][0] += wk[k] * a0;
            acc[k][1] += wk[k] * a1;
            acc[k][2] += wk[k] * a2;
            acc[k][3] += wk[k] * a3;
          }
        }
      }
    }
  }
  const int y = ty0 + tyy;
  #pragma unroll
  for (int k = 0; k < 8; ++k) {
    int ko = ko0 + tk8 + k;
    float bv = bias[ko];
    float4 v;
    v.x = fmaxf(acc[k][0] + bv, 0.f);
    v.y = fmaxf(acc[k][1] + bv, 0.f);
    v.z = fmaxf(acc[k][2] + bv, 0.f);
    v.w = fmaxf(acc[k][3] + bv, 0.f);
    *(float4*)&out[(((size_t)b * NC + ko) << 12) + y * 64 + tx0 + txx4] = v;
  }
}

// ---------------- 1x1 heads: 6 groups of 9 outputs, 2 positions/thread ----------------
// Channel-ascending accumulation order — bit-identical to the old head54_k.
__global__ __launch_bounds__(256) void head9_k(
    const float* __restrict__ conv, const float* __restrict__ Wcls,
    const float* __restrict__ bcls, const float* __restrict__ Wbbox,
    const float* __restrict__ bbbox, float* __restrict__ head) {
  __shared__ float Wl[9][68];
  const int b = blockIdx.z;
  const int g = blockIdx.y;                       // output group 0..5
  const int p0 = blockIdx.x * 512 + threadIdx.x;  // pos0; pos1 = p0 + 256
  const int tid = threadIdx.x;
  float acc0[9] = {}, acc1[9] = {};
  const float* cb = conv + ((size_t)b * NC << 12);
  for (int c0 = 0; c0 < NC; c0 += 64) {
    __syncthreads();
    for (int e = tid; e < 9 * 64; e += 256) {
      int o = e >> 6; int c = e & 63;
      int go = g * 9 + o;
      Wl[o][c] = (go < 18) ? Wcls[go * 512 + c0 + c] : Wbbox[(go - 18) * 512 + c0 + c];
    }
    __syncthreads();
    #pragma unroll 4
    for (int c = 0; c < 64; c += 4) {
      float v00 = cb[((size_t)(c0 + c + 0) << 12) + p0];
      float v01 = cb[((size_t)(c0 + c + 1) << 12) + p0];
      float v02 = cb[((size_t)(c0 + c + 2) << 12) + p0];
      float v03 = cb[((size_t)(c0 + c + 3) << 12) + p0];
      float v10 = cb[((size_t)(c0 + c + 0) << 12) + p0 + 256];
      float v11 = cb[((size_t)(c0 + c + 1) << 12) + p0 + 256];
      float v12 = cb[((size_t)(c0 + c + 2) << 12) + p0 + 256];
      float v13 = cb[((size_t)(c0 + c + 3) << 12) + p0 + 256];
      #pragma unroll
      for (int o = 0; o < 9; ++o) {
        const float4 w = *(const float4*)&Wl[o][c];
        acc0[o] += w.x * v00; acc0[o] += w.y * v01; acc0[o] += w.z * v02; acc0[o] += w.w * v03;
        acc1[o] += w.x * v10; acc1[o] += w.y * v11; acc1[o] += w.z * v12; acc1[o] += w.w * v13;
      }
    }
  }
  #pragma unroll
  for (int o = 0; o < 9; ++o) {
    int go = g * 9 + o;
    float bv = (go < 18) ? bcls[go] : bbbox[go - 18];
    head[(((size_t)b * 54 + go) << 12) + p0]       = acc0[o] + bv;
    head[(((size_t)b * 54 + go) << 12) + p0 + 256] = acc1[o] + bv;
  }
}

// ---------------- score + box decode + clip + coarse histogram ----------------
__global__ __launch_bounds__(256) void decode_k(
    const float* __restrict__ head, const float* __restrict__ im_info,
    float* __restrict__ boxes, unsigned* __restrict__ skeys, unsigned* __restrict__ hist) {
  int t = blockIdx.x * 256 + threadIdx.x;
  if (t >= NB * NANCH) return;
  int b = t / NANCH; int n = t - b * NANCH;
  int a = n % 9; int pos = n / 9;
  int x = pos & 63; int y = pos >> 6;
  const float* hb = head + ((size_t)b * 54 << 12);
  float s0 = hb[(a << 12) + pos];
  float s1 = hb[((9 + a) << 12) + pos];
  float m = fmaxf(s0, s1);
  float e0 = expf(s0 - m), e1 = expf(s1 - m);
  float score = e1 / (e0 + e1);
  int dbase = 18 + a * 4;
  float d0 = hb[((dbase + 0) << 12) + pos];
  float d1 = hb[((dbase + 1) << 12) + pos];
  float d2 = hb[((dbase + 2) << 12) + pos];
  float d3 = hb[((dbase + 3) << 12) + pos];
  float sx = x * 16.f, sy = y * 16.f;
  float ax1 = A9c[a][0] + sx, ay1 = A9c[a][1] + sy;
  float ax2 = A9c[a][2] + sx, ay2 = A9c[a][3] + sy;
  float aw = ax2 - ax1 + 1.f, ah = ay2 - ay1 + 1.f;
  float acx = ax1 + 0.5f * aw, acy = ay1 + 0.5f * ah;
  float pcx = d0 * aw + acx, pcy = d1 * ah + acy;
  float pw = expf(d2) * aw, ph = expf(d3) * ah;
  float imh = im_info[b * 3 + 0], imw = im_info[b * 3 + 1];
  float x1 = fminf(fmaxf(pcx - 0.5f * pw, 0.f), imw - 1.f);
  float y1 = fminf(fmaxf(pcy - 0.5f * ph, 0.f), imh - 1.f);
  float x2 = fminf(fmaxf(pcx + 0.5f * pw, 0.f), imw - 1.f);
  float y2 = fminf(fmaxf(pcy + 0.5f * ph, 0.f), imh - 1.f);
  *(float4*)&boxes[(size_t)t * 4] = make_float4(x1, y1, x2, y2);
  unsigned key = __float_as_uint(score);  // score>0 -> bits order == value order
  skeys[t] = key;
  atomicAdd(&hist[b * 4096 + (key >> 20)], 1u);
}

// ---------------- threshold select (2-level radix on float bits) ----------------
__global__ __launch_bounds__(256) void scan_hist_k(const unsigned* __restrict__ hist,
                                                  unsigned* __restrict__ misc) {
  int b = blockIdx.x;
  const unsigned* h = hist + b * 4096;
  __shared__ unsigned csum[256];
  int tid = threadIdx.x;
  unsigned s = 0;
  #pragma unroll
  for (int i = 0; i < 16; ++i) s += h[tid * 16 + i];
  csum[tid] = s;
  __syncthreads();
  if (tid == 0) {
    unsigned cum = 0; int chunk = 0;
    for (int c = 255; c >= 0; --c) {
      if (cum + csum[c] >= (unsigned)PRE_TOPN) { chunk = c; break; }
      cum += csum[c];
    }
    unsigned t1 = chunk * 16, cumAbove = cum;
    for (int i = 15; i >= 0; --i) {
      unsigned cnt = h[chunk * 16 + i];
      if (cum + cnt >= (unsigned)PRE_TOPN) { t1 = chunk * 16 + i; cumAbove = cum; break; }
      cum += cnt;
    }
    misc[b] = t1;          // boundary bin (top 12 bits)
    misc[4 + b] = cumAbove;
  }
}

__global__ __launch_bounds__(256) void hist2_k(const unsigned* __restrict__ skeys,
                                              const unsigned* __restrict__ misc,
                                              unsigned* __restrict__ hist2) {
  int t = blockIdx.x * 256 + threadIdx.x;
  if (t >= NB * NANCH) return;
  int b = t / NANCH;
  unsigned key = skeys[t];
  if ((key >> 20) == misc[b]) atomicAdd(&hist2[b * 256 + ((key >> 12) & 255u)], 1u);
}

__global__ void scan2_k(const unsigned* __restrict__ hist2, unsigned* __restrict__ misc) {
  int b = blockIdx.x;
  if (threadIdx.x != 0) return;
  unsigned cum = misc[4 + b];
  unsigned t1 = misc[b];
  unsigned T2 = t1 << 20;
  for (int s = 255; s >= 0; --s) {
    unsigned c = hist2[b * 256 + s];
    if (cum + c >= (unsigned)PRE_TOPN) { T2 = (t1 << 20) | ((unsigned)s << 12); break; }
    cum += c;
  }
  misc[8 + b] = T2;
}

__global__ __launch_bounds__(256) void compact_k(const unsigned* __restrict__ skeys,
                                                unsigned* __restrict__ misc,
                                                unsigned* __restrict__ ckey,
                                                unsigned* __restrict__ cidx) {
  int t = blockIdx.x * 256 + threadIdx.x;
  if (t >= NB * NANCH) return;
  int b = t / NANCH; int n = t - b * NANCH;
  unsigned key = skeys[t];
  if (key >= misc[8 + b]) {
    unsigned p = atomicAdd(&misc[12 + b], 1u);
    if (p < (unsigned)CAND_CAP) {
      ckey[(size_t)b * CAND_CAP + p] = key;
      cidx[(size_t)b * CAND_CAP + p] = (unsigned)n;
    }
  }
}

// ---------------- exact rank sort of candidates (desc score, asc index) ----------------
__global__ __launch_bounds__(256) void rank_scatter_k(
    const unsigned* __restrict__ ckey, const unsigned* __restrict__ cidx,
    const unsigned* __restrict__ misc, const float* __restrict__ boxes,
    float* __restrict__ sbox) {
  const int b = blockIdx.y;
  const int K = min((int)misc[12 + b], CAND_CAP);
  const int i = blockIdx.x * 256 + threadIdx.x;
  unsigned mykey = 0, myidx = 0;
  const bool active = i < K;
  if (active) {
    mykey = ckey[(size_t)b * CAND_CAP + i];
    myidx = cidx[(size_t)b * CAND_CAP + i];
  }
  int rank = 0;
  __shared__ unsigned skey[1024];
  __shared__ unsigned sidx[1024];
  for (int c0 = 0; c0 < K; c0 += 1024) {
    int n = min(1024, K - c0);
    __syncthreads();
    for (int e = threadIdx.x; e < n; e += 256) {
      skey[e] = ckey[(size_t)b * CAND_CAP + c0 + e];
      sidx[e] = cidx[(size_t)b * CAND_CAP + c0 + e];
    }
    __syncthreads();
    if (active) {
      for (int j = 0; j < n; ++j) {
        unsigned kj = skey[j];
        rank += (kj > mykey) || (kj == mykey && sidx[j] < myidx);
      }
    }
  }
  if (active && rank < PRE_TOPN) {
    float4 bx = *(const float4*)&boxes[((size_t)b * NANCH + myidx) * 4];
    *(float4*)&sbox[((size_t)b * PRE_TOPN + rank) * 4] = bx;
  }
}

// ---------------- IoU suppression bit-matrix: mask[b][i][w] bit q = (iou(i, w*64+q) > 0.7) --
__global__ __launch_bounds__(256) void iou_mask_k(const float* __restrict__ sbox,
                                                  unsigned long long* __restrict__ mask) {
  __shared__ float4 jb[3008];  // 48 KiB j-tile
  __shared__ float4 ib[32];    // i-tile
  const int b  = blockIdx.z;
  const int i0 = blockIdx.y * 32;
  const int w0 = blockIdx.x * 47;
  const int j0 = w0 * 64;
  const int nj = min(3008, PRE_TOPN - j0);
  const int tid = threadIdx.x;
  const float4* S = (const float4*)(sbox + (size_t)b * PRE_TOPN * 4);
  for (int e = tid; e < nj; e += 256) jb[e] = S[j0 + e];
  if (tid < 32 && i0 + tid < PRE_TOPN) ib[tid] = S[i0 + tid];
  __syncthreads();
  for (int idx = tid; idx < 32 * 47; idx += 256) {
    const int il = idx / 47, wl = idx - il * 47;
    const int i = i0 + il;
    if (i >= PRE_TOPN) continue;
    const float4 p = ib[il];
    const float parea = (p.z - p.x + 1.f) * (p.w - p.y + 1.f);
    unsigned long long m = 0;
    const int jb0 = wl * 64;
    #pragma unroll 8
    for (int q = 0; q < 64; ++q) {
      const int j = jb0 + q;   // j <= 46*64+63 = 3007 < 3008: always in-bounds
      const float4 qb = jb[j];
      float xx1 = fmaxf(p.x, qb.x), yy1 = fmaxf(p.y, qb.y);
      float xx2 = fminf(p.z, qb.z), yy2 = fminf(p.w, qb.w);
      float inter = fmaxf(xx2 - xx1 + 1.f, 0.f) * fmaxf(yy2 - yy1 + 1.f, 0.f);
      float area = (qb.z - qb.x + 1.f) * (qb.w - qb.y + 1.f);
      float iou = inter / (parea + area - inter);
      if (iou > 0.7f && j < nj) m |= (1ull << q);
    }
    mask[((size_t)b * PRE_TOPN + i) * MROW + w0 + wl] = m;
  }
}

// ---------------- wave-synchronous greedy pick: valid bitset in VGPRs ----------------
__device__ inline unsigned long long shfl_u64(unsigned long long v, int src) {
  int lo = __shfl((int)(unsigned)v, src, 64);
  int hi = __shfl((int)(unsigned)(v >> 32), src, 64);
  return ((unsigned long long)(unsigned)hi << 32) | (unsigned)lo;
}

__global__ __launch_bounds__(64) void nms_pick_k(const float* __restrict__ sbox,
                                                 const unsigned long long* __restrict__ mask,
                                                 float* __restrict__ out) {
  const int b = blockIdx.x;
  const int lane = threadIdx.x;
  unsigned long long va = ~0ull;
  unsigned long long vb = (lane < 29) ? ~0ull : (lane == 29 ? ((1ull << 48) - 1ull) : 0ull);
  const float* Bb = sbox + (size_t)b * PRE_TOPN * 4;
  float* O = out + (size_t)b * POST_TOPN * 5;
  int done = POST_TOPN;
  for (int it = 0; it < POST_TOPN; ++it) {
    unsigned long long ba = __ballot(va != 0ull);
    unsigned long long bb = __ballot(vb != 0ull);
    int w; unsigned long long word;
    if (ba) {
      w = __ffsll((long long)ba) - 1;
      word = shfl_u64(va, w);
    } else if (bb) {
      w = __ffsll((long long)bb) - 1;
      word = shfl_u64(vb, w);
      w += 64;
    } else { done = it; break; }
    const int i = (w << 6) + __ffsll((long long)word) - 1;
    const unsigned long long* row = mask + ((size_t)b * PRE_TOPN + i) * MROW;
    unsigned long long ra = row[lane];
    unsigned long long rb = (lane < 30) ? row[64 + lane] : 0ull;
    if (lane < 4) O[it * 5 + 1 + lane] = Bb[(size_t)i * 4 + lane];
    if (lane == 4) O[it * 5] = (float)b;
    va &= ~ra;
    vb &= ~rb;
  }
  for (int e = lane; e < (POST_TOPN - done) * 5; e += 64) {
    int r = done + e / 5; int c = e - (e / 5) * 5;
    O[r * 5 + c] = (c == 0) ? (float)b : 0.f;
  }
}

// ---------------- launch ----------------
extern "C" void kernel_launch(void* const* d_in, const int* in_sizes, int n_in,
                              void* d_out, int out_size, void* d_ws, size_t ws_size,
                              hipStream_t stream) {
  const float* base_feat = (const float*)d_in[0];
  const float* im_info   = (const float*)d_in[1];
  const float* W_conv    = (const float*)d_in[4];
  const float* b_conv    = (const float*)d_in[5];
  const float* W_cls     = (const float*)d_in[6];
  const float* b_cls     = (const float*)d_in[7];
  const float* W_bbox    = (const float*)d_in[8];
  const float* b_bbox    = (const float*)d_in[9];
  float* out = (float*)d_out;
  char* ws = (char*)d_ws;

  float*    Wt    = (float*)(ws + OFF_WT);
  float*    conv  = (float*)(ws + OFF_CONV);
  unsigned long long* mask = (unsigned long long*)(ws + OFF_MASK);  // overlays conv (dead after heads)
  float*    head  = (float*)(ws + OFF_HEAD);
  unsigned* skeys = (unsigned*)(ws + OFF_SKEY);
  float*    boxes = (float*)(ws + OFF_BOX);
  unsigned* hist  = (unsigned*)(ws + OFF_HIST);
  unsigned* hist2 = (unsigned*)(ws + OFF_HIST2);
  unsigned* misc  = (unsigned*)(ws + OFF_MISC);
  unsigned* ckey  = (unsigned*)(ws + OFF_CKEY);
  unsigned* cidx  = (unsigned*)(ws + OFF_CIDX);
  float*    sbox  = (float*)(ws + OFF_SBOX);

  // zero hist + hist2 + misc (contiguous)
  hipMemsetAsync(ws + OFF_HIST, 0, 65536 + 4096 + 256, stream);

  wtrans_k<<<(512 * 512 * 9 + 255) / 256, 256, 0, stream>>>(W_conv, Wt);
  conv3x3_relu_k<<<dim3(8, 32, 4), 256, 0, stream>>>(base_feat, Wt, b_conv, conv);
  head9_k<<<dim3(8, 6, 4), 256, 0, stream>>>(conv, W_cls, b_cls, W_bbox, b_bbox, head);
  decode_k<<<(NB * NANCH) / 256, 256, 0, stream>>>(head, im_info, boxes, skeys, hist);
  scan_hist_k<<<4, 256, 0, stream>>>(hist, misc);
  hist2_k<<<(NB * NANCH) / 256, 256, 0, stream>>>(skeys, misc, hist2);
  scan2_k<<<4, 64, 0, stream>>>(hist2, misc);
  compact_k<<<(NB * NANCH) / 256, 256, 0, stream>>>(skeys, misc, ckey, cidx);
  rank_scatter_k<<<dim3(CAND_CAP / 256, 4), 256, 0, stream>>>(ckey, cidx, misc, boxes, sbox);
  iou_mask_k<<<dim3(2, 188, 4), 256, 0, stream>>>(sbox, mask);
  nms_pick_k<<<4, 64, 0, stream>>>(sbox, mask, out);
}

// Round 5
// 1818.789 us; speedup vs baseline: 2.3980x; 1.2951x over previous
//
#include <hip/hip_runtime.h>
#include <math.h>

// ---------------- problem constants ----------------
constexpr int NB = 4;            // batch
constexpr int NC = 512;          // channels
constexpr int NH = 64, NW = 64;  // spatial
constexpr int NPOS = NH * NW;        // 4096
constexpr int NANCH = NPOS * 9;      // 36864 anchors/batch
constexpr int PRE_TOPN = 6000;
constexpr int POST_TOPN = 300;
constexpr int CAND_CAP = 40960;
constexpr int MROW = 96;             // mask row stride in u64 (94 used)

// anchors for base_size=16, ratios {0.5,1,2}, scales {8,16,32} (verified vs numpy)
__device__ __constant__ float A9c[9][4] = {
  {-84.f,-40.f,99.f,55.f},   {-176.f,-88.f,191.f,103.f}, {-360.f,-184.f,375.f,199.f},
  {-56.f,-56.f,71.f,71.f},   {-120.f,-120.f,135.f,135.f},{-248.f,-248.f,263.f,263.f},
  {-36.f,-80.f,51.f,95.f},   {-80.f,-168.f,95.f,183.f},  {-168.f,-344.f,183.f,359.f}};

// ---------------- ws layout (bytes) ----------------
constexpr size_t OFF_WT    = 0;                       // 512*512*9*4      = 9,437,184
constexpr size_t OFF_CONV  = 9437184;                 // 4*512*4096*4     = 33,554,432 (reused as IoU mask after heads)
constexpr size_t OFF_MASK  = OFF_CONV;                // 4*6000*96*8      = 18,432,000 (overlay)
constexpr size_t OFF_HEAD  = 42991616;                // 4*54*4096*4      = 3,538,944
constexpr size_t OFF_SKEY  = 46530560;                // 4*36864*4        = 589,824
constexpr size_t OFF_BOX   = 47120384;                // 4*36864*4*4      = 2,359,296
constexpr size_t OFF_HIST  = 49479680;                // 4*4096*4         = 65,536
constexpr size_t OFF_HIST2 = 49545216;                // 4*256*4          = 4,096
constexpr size_t OFF_MISC  = 49549312;                // 256
constexpr size_t OFF_CKEY  = 49549568;                // 4*40960*4        = 655,360
constexpr size_t OFF_CIDX  = 50204928;                // 4*40960*4        = 655,360
constexpr size_t OFF_SBOX  = 50860288;                // 4*6000*4*4       = 384,000
// total ≈ 51.2 MB

// ---------------- weight transpose: W[ko][c][tap] -> Wt[c][tap][ko] ----------------
__global__ __launch_bounds__(256) void wtrans_k(const float* __restrict__ Wc,
                                               float* __restrict__ Wt) {
  int i = blockIdx.x * 256 + threadIdx.x;
  if (i >= 512 * 512 * 9) return;
  int ko = i / 4608; int r = i - ko * 4608; int c = r / 9; int tap = r - c * 9;
  Wt[((size_t)c * 9 + tap) * 512 + ko] = Wc[i];
}

// ---------------- 3x3 conv + bias + relu (fp32, 8ko x 8x per thread) ----------------
// Per-output accumulation order: c ascending, dy ascending, dx ascending —
// bit-identical to the R1/R3/R4-passing kernels (selection depends on exact fp32 bits).
__global__ __launch_bounds__(256, 2) void conv3x3_relu_k(
    const float* __restrict__ in, const float* __restrict__ Wt,
    const float* __restrict__ bias, float* __restrict__ out) {
  __shared__ float Ilds[8][10][36];   // c, y+halo, x+halo (34 used, pad->36 keeps 16B align)
  __shared__ float Wlds[8][9][64];    // c, tap, ko  (flat-linear staging)
  const int ko0 = blockIdx.x * 64;        // 8 ko-blocks
  const int ty0 = (blockIdx.y >> 1) * 8;  // 8 y-tiles
  const int tx0 = (blockIdx.y & 1) * 32;  // 2 x-tiles
  const int b   = blockIdx.z;
  const int tid = threadIdx.x;
  const int tk8  = (tid & 7) * 8;      // 8 kout per thread
  const int tyy  = (tid >> 3) & 7;     // row within tile
  const int txx8 = (tid >> 6) * 8;     // 8 x per thread

  float acc[8][8] = {};
  const float* inb = in + (size_t)b * NC * NPOS;

  for (int c0 = 0; c0 < NC; c0 += 8) {
    __syncthreads();
    // stage input patch 8 x 10 x 34 (2720 elems); index math is c0-invariant (hoisted)
    for (int e = tid; e < 8 * 10 * 34; e += 256) {
      int cc = e / 340; int rem = e - cc * 340; int yy = rem / 34; int xx = rem - yy * 34;
      int gy = ty0 + yy - 1, gx = tx0 + xx - 1;
      float v = 0.f;
      if ((unsigned)gy < 64u && (unsigned)gx < 64u)
        v = inb[(size_t)(c0 + cc) * NPOS + gy * 64 + gx];
      Ilds[cc][yy][xx] = v;
    }
    // stage weights 8 x 9 x 64 = 4608 elems; destination linear in e
    for (int e = tid; e < 8 * 9 * 64; e += 256) {
      int ko = e & 63; int r = e >> 6; int tap = r % 9; int cc = r / 9;
      ((float*)Wlds)[e] = Wt[(size_t)(c0 + cc) * 4608 + tap * 512 + ko0 + ko];
    }
    __syncthreads();
    #pragma unroll 2
    for (int cc = 0; cc < 8; ++cc) {
      #pragma unroll
      for (int dy = 0; dy < 3; ++dy) {
        const float* ir = &Ilds[cc][tyy + dy][txx8];
        const float4 A0 = *(const float4*)&ir[0];
        const float4 A1 = *(const float4*)&ir[4];
        const float2 A2 = *(const float2*)&ir[8];
        const float av[10] = {A0.x,A0.y,A0.z,A0.w,A1.x,A1.y,A1.z,A1.w,A2.x,A2.y};
        #pragma unroll
        for (int dx = 0; dx < 3; ++dx) {
          const float4 wa = *(const float4*)&Wlds[cc][dy * 3 + dx][tk8];
          const float4 wb = *(const float4*)&Wlds[cc][dy * 3 + dx][tk8 + 4];
          const float wk[8] = {wa.x, wa.y, wa.z, wa.w, wb.x, wb.y, wb.z, wb.w};
          #pragma unroll
          for (int k = 0; k < 8; ++k) {
            #pragma unroll
            for (int x = 0; x < 8; ++x) {
              acc[k][x] += wk[k] * av[dx + x];
            }
          }
        }
      }
    }
  }
  const int y = ty0 + tyy;
  #pragma unroll
  for (int k = 0; k < 8; ++k) {
    int ko = ko0 + tk8 + k;
    float bv = bias[ko];
    float4 v0, v1;
    v0.x = fmaxf(acc[k][0] + bv, 0.f);
    v0.y = fmaxf(acc[k][1] + bv, 0.f);
    v0.z = fmaxf(acc[k][2] + bv, 0.f);
    v0.w = fmaxf(acc[k][3] + bv, 0.f);
    v1.x = fmaxf(acc[k][4] + bv, 0.f);
    v1.y = fmaxf(acc[k][5] + bv, 0.f);
    v1.z = fmaxf(acc[k][6] + bv, 0.f);
    v1.w = fmaxf(acc[k][7] + bv, 0.f);
    float* op = &out[(((size_t)b * NC + ko) << 12) + y * 64 + tx0 + txx8];
    *(float4*)&op[0] = v0;
    *(float4*)&op[4] = v1;
  }
}

// ---------------- 1x1 heads: 6 groups of 9 outputs, 2 positions/thread ----------------
// Channel-ascending accumulation order — bit-identical to head54_k.
__global__ __launch_bounds__(256) void head9_k(
    const float* __restrict__ conv, const float* __restrict__ Wcls,
    const float* __restrict__ bcls, const float* __restrict__ Wbbox,
    const float* __restrict__ bbbox, float* __restrict__ head) {
  __shared__ float Wl[9][68];
  const int b = blockIdx.z;
  const int g = blockIdx.y;                       // output group 0..5
  const int p0 = blockIdx.x * 512 + threadIdx.x;  // pos0; pos1 = p0 + 256
  const int tid = threadIdx.x;
  float acc0[9] = {}, acc1[9] = {};
  const float* cb = conv + ((size_t)b * NC << 12);
  for (int c0 = 0; c0 < NC; c0 += 64) {
    __syncthreads();
    for (int e = tid; e < 9 * 64; e += 256) {
      int o = e >> 6; int c = e & 63;
      int go = g * 9 + o;
      Wl[o][c] = (go < 18) ? Wcls[go * 512 + c0 + c] : Wbbox[(go - 18) * 512 + c0 + c];
    }
    __syncthreads();
    #pragma unroll 4
    for (int c = 0; c < 64; c += 4) {
      float v00 = cb[((size_t)(c0 + c + 0) << 12) + p0];
      float v01 = cb[((size_t)(c0 + c + 1) << 12) + p0];
      float v02 = cb[((size_t)(c0 + c + 2) << 12) + p0];
      float v03 = cb[((size_t)(c0 + c + 3) << 12) + p0];
      float v10 = cb[((size_t)(c0 + c + 0) << 12) + p0 + 256];
      float v11 = cb[((size_t)(c0 + c + 1) << 12) + p0 + 256];
      float v12 = cb[((size_t)(c0 + c + 2) << 12) + p0 + 256];
      float v13 = cb[((size_t)(c0 + c + 3) << 12) + p0 + 256];
      #pragma unroll
      for (int o = 0; o < 9; ++o) {
        const float4 w = *(const float4*)&Wl[o][c];
        acc0[o] += w.x * v00; acc0[o] += w.y * v01; acc0[o] += w.z * v02; acc0[o] += w.w * v03;
        acc1[o] += w.x * v10; acc1[o] += w.y * v11; acc1[o] += w.z * v12; acc1[o] += w.w * v13;
      }
    }
  }
  #pragma unroll
  for (int o = 0; o < 9; ++o) {
    int go = g * 9 + o;
    float bv = (go < 18) ? bcls[go] : bbbox[go - 18];
    head[(((size_t)b * 54 + go) << 12) + p0]       = acc0[o] + bv;
    head[(((size_t)b * 54 + go) << 12) + p0 + 256] = acc1[o] + bv;
  }
}

// ---------------- score + box decode + clip + LDS histogram ----------------
// NANCH % 256 == 0, so each block lies entirely in one batch.
__global__ __launch_bounds__(256) void decode_k(
    const float* __restrict__ head, const float* __restrict__ im_info,
    float* __restrict__ boxes, unsigned* __restrict__ skeys, unsigned* __restrict__ hist) {
  __shared__ unsigned hl[4096];
  const int tid = threadIdx.x;
  #pragma unroll
  for (int i = 0; i < 16; ++i) hl[tid + i * 256] = 0u;
  __syncthreads();
  int t = blockIdx.x * 256 + tid;
  int b = t / NANCH; int n = t - b * NANCH;
  int a = n % 9; int pos = n / 9;
  int x = pos & 63; int y = pos >> 6;
  const float* hb = head + ((size_t)b * 54 << 12);
  float s0 = hb[(a << 12) + pos];
  float s1 = hb[((9 + a) << 12) + pos];
  float m = fmaxf(s0, s1);
  float e0 = expf(s0 - m), e1 = expf(s1 - m);
  float score = e1 / (e0 + e1);
  int dbase = 18 + a * 4;
  float d0 = hb[((dbase + 0) << 12) + pos];
  float d1 = hb[((dbase + 1) << 12) + pos];
  float d2 = hb[((dbase + 2) << 12) + pos];
  float d3 = hb[((dbase + 3) << 12) + pos];
  float sx = x * 16.f, sy = y * 16.f;
  float ax1 = A9c[a][0] + sx, ay1 = A9c[a][1] + sy;
  float ax2 = A9c[a][2] + sx, ay2 = A9c[a][3] + sy;
  float aw = ax2 - ax1 + 1.f, ah = ay2 - ay1 + 1.f;
  float acx = ax1 + 0.5f * aw, acy = ay1 + 0.5f * ah;
  float pcx = d0 * aw + acx, pcy = d1 * ah + acy;
  float pw = expf(d2) * aw, ph = expf(d3) * ah;
  float imh = im_info[b * 3 + 0], imw = im_info[b * 3 + 1];
  float x1 = fminf(fmaxf(pcx - 0.5f * pw, 0.f), imw - 1.f);
  float y1 = fminf(fmaxf(pcy - 0.5f * ph, 0.f), imh - 1.f);
  float x2 = fminf(fmaxf(pcx + 0.5f * pw, 0.f), imw - 1.f);
  float y2 = fminf(fmaxf(pcy + 0.5f * ph, 0.f), imh - 1.f);
  *(float4*)&boxes[(size_t)t * 4] = make_float4(x1, y1, x2, y2);
  unsigned key = __float_as_uint(score);  // score>0 -> bits order == value order
  skeys[t] = key;
  atomicAdd(&hl[key >> 20], 1u);
  __syncthreads();
  // merge non-zero bins to global (scores cluster -> few non-zero bins per block)
  #pragma unroll
  for (int i = 0; i < 16; ++i) {
    unsigned c = hl[tid + i * 256];
    if (c) atomicAdd(&hist[b * 4096 + tid + i * 256], c);
  }
}

// ---------------- threshold select (2-level radix on float bits) ----------------
__global__ __launch_bounds__(256) void scan_hist_k(const unsigned* __restrict__ hist,
                                                  unsigned* __restrict__ misc) {
  int b = blockIdx.x;
  const unsigned* h = hist + b * 4096;
  __shared__ unsigned csum[256];
  int tid = threadIdx.x;
  unsigned s = 0;
  #pragma unroll
  for (int i = 0; i < 16; ++i) s += h[tid * 16 + i];
  csum[tid] = s;
  __syncthreads();
  if (tid == 0) {
    unsigned cum = 0; int chunk = 0;
    for (int c = 255; c >= 0; --c) {
      if (cum + csum[c] >= (unsigned)PRE_TOPN) { chunk = c; break; }
      cum += csum[c];
    }
    unsigned t1 = chunk * 16, cumAbove = cum;
    for (int i = 15; i >= 0; --i) {
      unsigned cnt = h[chunk * 16 + i];
      if (cum + cnt >= (unsigned)PRE_TOPN) { t1 = chunk * 16 + i; cumAbove = cum; break; }
      cum += cnt;
    }
    misc[b] = t1;          // boundary bin (top 12 bits)
    misc[4 + b] = cumAbove;
  }
}

__global__ __launch_bounds__(256) void hist2_k(const unsigned* __restrict__ skeys,
                                              const unsigned* __restrict__ misc,
                                              unsigned* __restrict__ hist2) {
  int t = blockIdx.x * 256 + threadIdx.x;
  if (t >= NB * NANCH) return;
  int b = t / NANCH;
  unsigned key = skeys[t];
  if ((key >> 20) == misc[b]) atomicAdd(&hist2[b * 256 + ((key >> 12) & 255u)], 1u);
}

__global__ void scan2_k(const unsigned* __restrict__ hist2, unsigned* __restrict__ misc) {
  int b = blockIdx.x;
  if (threadIdx.x != 0) return;
  unsigned cum = misc[4 + b];
  unsigned t1 = misc[b];
  unsigned T2 = t1 << 20;
  for (int s = 255; s >= 0; --s) {
    unsigned c = hist2[b * 256 + s];
    if (cum + c >= (unsigned)PRE_TOPN) { T2 = (t1 << 20) | ((unsigned)s << 12); break; }
    cum += c;
  }
  misc[8 + b] = T2;
}

// ---------------- compact: wave-aggregated atomic ----------------
__global__ __launch_bounds__(256) void compact_k(const unsigned* __restrict__ skeys,
                                                unsigned* __restrict__ misc,
                                                unsigned* __restrict__ ckey,
                                                unsigned* __restrict__ cidx) {
  int t = blockIdx.x * 256 + threadIdx.x;
  int b = t / NANCH; int n = t - b * NANCH;   // b uniform per wave (NANCH % 64 == 0)
  unsigned key = skeys[t];
  bool pred = key >= misc[8 + b];
  unsigned long long mball = __ballot(pred);
  int lane = threadIdx.x & 63;
  unsigned cnt = (unsigned)__popcll(mball);
  unsigned base = 0;
  if (lane == 0 && cnt) base = atomicAdd(&misc[12 + b], cnt);
  base = (unsigned)__shfl((int)base, 0, 64);
  if (pred) {
    unsigned p = base + (unsigned)__popcll(mball & ((1ull << lane) - 1ull));
    if (p < (unsigned)CAND_CAP) {
      ckey[(size_t)b * CAND_CAP + p] = key;
      cidx[(size_t)b * CAND_CAP + p] = (unsigned)n;
    }
  }
}

// ---------------- exact rank sort of candidates (desc score, asc index) ----------------
__global__ __launch_bounds__(256) void rank_scatter_k(
    const unsigned* __restrict__ ckey, const unsigned* __restrict__ cidx,
    const unsigned* __restrict__ misc, const float* __restrict__ boxes,
    float* __restrict__ sbox) {
  const int b = blockIdx.y;
  const int K = min((int)misc[12 + b], CAND_CAP);
  const int i = blockIdx.x * 256 + threadIdx.x;
  unsigned mykey = 0, myidx = 0;
  const bool active = i < K;
  if (active) {
    mykey = ckey[(size_t)b * CAND_CAP + i];
    myidx = cidx[(size_t)b * CAND_CAP + i];
  }
  int rank = 0;
  __shared__ unsigned skey[1024];
  __shared__ unsigned sidx[1024];
  for (int c0 = 0; c0 < K; c0 += 1024) {
    int n = min(1024, K - c0);
    __syncthreads();
    for (int e = threadIdx.x; e < n; e += 256) {
      skey[e] = ckey[(size_t)b * CAND_CAP + c0 + e];
      sidx[e] = cidx[(size_t)b * CAND_CAP + c0 + e];
    }
    __syncthreads();
    if (active) {
      for (int j = 0; j < n; ++j) {
        unsigned kj = skey[j];
        rank += (kj > mykey) || (kj == mykey && sidx[j] < myidx);
      }
    }
  }
  if (active && rank < PRE_TOPN) {
    float4 bx = *(const float4*)&boxes[((size_t)b * NANCH + myidx) * 4];
    *(float4*)&sbox[((size_t)b * PRE_TOPN + rank) * 4] = bx;
  }
}

// ---------------- IoU suppression bit-matrix: mask[b][i][w] bit q = (iou(i, w*64+q) > 0.7) --
__global__ __launch_bounds__(256) void iou_mask_k(const float* __restrict__ sbox,
                                                  unsigned long long* __restrict__ mask) {
  __shared__ float4 jb[3008];  // 48 KiB j-tile
  __shared__ float4 ib[32];    // i-tile
  const int b  = blockIdx.z;
  const int i0 = blockIdx.y * 32;
  const int w0 = blockIdx.x * 47;
  const int j0 = w0 * 64;
  const int nj = min(3008, PRE_TOPN - j0);
  const int tid = threadIdx.x;
  const float4* S = (const float4*)(sbox + (size_t)b * PRE_TOPN * 4);
  for (int e = tid; e < nj; e += 256) jb[e] = S[j0 + e];
  if (tid < 32 && i0 + tid < PRE_TOPN) ib[tid] = S[i0 + tid];
  __syncthreads();
  for (int idx = tid; idx < 32 * 47; idx += 256) {
    const int il = idx / 47, wl = idx - il * 47;
    const int i = i0 + il;
    if (i >= PRE_TOPN) continue;
    const float4 p = ib[il];
    const float parea = (p.z - p.x + 1.f) * (p.w - p.y + 1.f);
    unsigned long long m = 0;
    const int jb0 = wl * 64;
    #pragma unroll 8
    for (int q = 0; q < 64; ++q) {
      const int j = jb0 + q;   // j <= 46*64+63 = 3007 < 3008: always in-bounds
      const float4 qb = jb[j];
      float xx1 = fmaxf(p.x, qb.x), yy1 = fmaxf(p.y, qb.y);
      float xx2 = fminf(p.z, qb.z), yy2 = fminf(p.w, qb.w);
      float inter = fmaxf(xx2 - xx1 + 1.f, 0.f) * fmaxf(yy2 - yy1 + 1.f, 0.f);
      float area = (qb.z - qb.x + 1.f) * (qb.w - qb.y + 1.f);
      float iou = inter / (parea + area - inter);
      if (iou > 0.7f && j < nj) m |= (1ull << q);
    }
    mask[((size_t)b * PRE_TOPN + i) * MROW + w0 + wl] = m;
  }
}

// ---------------- wave-synchronous greedy pick: valid bitset in VGPRs ----------------
__device__ inline unsigned long long shfl_u64(unsigned long long v, int src) {
  int lo = __shfl((int)(unsigned)v, src, 64);
  int hi = __shfl((int)(unsigned)(v >> 32), src, 64);
  return ((unsigned long long)(unsigned)hi << 32) | (unsigned)lo;
}

__global__ __launch_bounds__(64) void nms_pick_k(const float* __restrict__ sbox,
                                                 const unsigned long long* __restrict__ mask,
                                                 float* __restrict__ out) {
  const int b = blockIdx.x;
  const int lane = threadIdx.x;
  unsigned long long va = ~0ull;
  unsigned long long vb = (lane < 29) ? ~0ull : (lane == 29 ? ((1ull << 48) - 1ull) : 0ull);
  const float* Bb = sbox + (size_t)b * PRE_TOPN * 4;
  float* O = out + (size_t)b * POST_TOPN * 5;
  int done = POST_TOPN;
  for (int it = 0; it < POST_TOPN; ++it) {
    unsigned long long ba = __ballot(va != 0ull);
    unsigned long long bb = __ballot(vb != 0ull);
    int w; unsigned long long word;
    if (ba) {
      w = __ffsll((long long)ba) - 1;
      word = shfl_u64(va, w);
    } else if (bb) {
      w = __ffsll((long long)bb) - 1;
      word = shfl_u64(vb, w);
      w += 64;
    } else { done = it; break; }
    const int i = (w << 6) + __ffsll((long long)word) - 1;
    const unsigned long long* row = mask + ((size_t)b * PRE_TOPN + i) * MROW;
    unsigned long long ra = row[lane];
    unsigned long long rb = (lane < 30) ? row[64 + lane] : 0ull;
    if (lane < 4) O[it * 5 + 1 + lane] = Bb[(size_t)i * 4 + lane];
    if (lane == 4) O[it * 5] = (float)b;
    va &= ~ra;
    vb &= ~rb;
  }
  for (int e = lane; e < (POST_TOPN - done) * 5; e += 64) {
    int r = done + e / 5; int c = e - (e / 5) * 5;
    O[r * 5 + c] = (c == 0) ? (float)b : 0.f;
  }
}

// ---------------- launch ----------------
extern "C" void kernel_launch(void* const* d_in, const int* in_sizes, int n_in,
                              void* d_out, int out_size, void* d_ws, size_t ws_size,
                              hipStream_t stream) {
  const float* base_feat = (const float*)d_in[0];
  const float* im_info   = (const float*)d_in[1];
  const float* W_conv    = (const float*)d_in[4];
  const float* b_conv    = (const float*)d_in[5];
  const float* W_cls     = (const float*)d_in[6];
  const float* b_cls     = (const float*)d_in[7];
  const float* W_bbox    = (const float*)d_in[8];
  const float* b_bbox    = (const float*)d_in[9];
  float* out = (float*)d_out;
  char* ws = (char*)d_ws;

  float*    Wt    = (float*)(ws + OFF_WT);
  float*    conv  = (float*)(ws + OFF_CONV);
  unsigned long long* mask = (unsigned long long*)(ws + OFF_MASK);  // overlays conv (dead after heads)
  float*    head  = (float*)(ws + OFF_HEAD);
  unsigned* skeys = (unsigned*)(ws + OFF_SKEY);
  float*    boxes = (float*)(ws + OFF_BOX);
  unsigned* hist  = (unsigned*)(ws + OFF_HIST);
  unsigned* hist2 = (unsigned*)(ws + OFF_HIST2);
  unsigned* misc  = (unsigned*)(ws + OFF_MISC);
  unsigned* ckey  = (unsigned*)(ws + OFF_CKEY);
  unsigned* cidx  = (unsigned*)(ws + OFF_CIDX);
  float*    sbox  = (float*)(ws + OFF_SBOX);

  // zero hist + hist2 + misc (contiguous)
  hipMemsetAsync(ws + OFF_HIST, 0, 65536 + 4096 + 256, stream);

  wtrans_k<<<(512 * 512 * 9 + 255) / 256, 256, 0, stream>>>(W_conv, Wt);
  conv3x3_relu_k<<<dim3(8, 16, 4), 256, 0, stream>>>(base_feat, Wt, b_conv, conv);
  head9_k<<<dim3(8, 6, 4), 256, 0, stream>>>(conv, W_cls, b_cls, W_bbox, b_bbox, head);
  decode_k<<<(NB * NANCH) / 256, 256, 0, stream>>>(head, im_info, boxes, skeys, hist);
  scan_hist_k<<<4, 256, 0, stream>>>(hist, misc);
  hist2_k<<<(NB * NANCH) / 256, 256, 0, stream>>>(skeys, misc, hist2);
  scan2_k<<<4, 64, 0, stream>>>(hist2, misc);
  compact_k<<<(NB * NANCH) / 256, 256, 0, stream>>>(skeys, misc, ckey, cidx);
  rank_scatter_k<<<dim3(CAND_CAP / 256, 4), 256, 0, stream>>>(ckey, cidx, misc, boxes, sbox);
  iou_mask_k<<<dim3(2, 188, 4), 256, 0, stream>>>(sbox, mask);
  nms_pick_k<<<4, 64, 0, stream>>>(sbox, mask, out);
}